// Round 13
// baseline (153.928 us; speedup 1.0000x reference)
//
#include <hip/hip_runtime.h>
#include <math.h>
#include <stdint.h>

// MultipleTopoTreeLoss = mean over 32 (sample,chunk) pairs of sum of squared
// Euclidean-MST edge lengths of 1024 standardized 3-D points.  Boruvka,
// fused combine(rd-1)+scan(rd) per dispatch (r11 structure, 145.6us, best).
//
// r11 post-mortem: profile top-5 = harness's fixed ~45us ws poison fill; our
// net ~100us.  Two fixes this round:
//  1) r11 latent race: part0 wrote labels while sibling blocks of the same
//     sample read them (safe only by co-start timing).  Now labels are
//     parity-double-buffered: round rd reads glab[(rd-1)&1], writes
//     glab[rd&1]; k0 writes identity into glab[0].  No intra-dispatch
//     cross-block read/write overlap anywhere.
//  2) late-round waste: a live dispatch cost ~9us even with 1 live sample
//     (static 8 blocks/sample).  Now each round's combine appends live
//     samples to live_list[rd] (atomicAdd order nondeterministic, contents
//     deterministic); next dispatch assigns B=32/16/8 blocks per live sample
//     (B=32 if n_live<=8, 16 if <=16, else 8), scan templated on NG=32/B
//     nodes-per-group.  Straggler rounds ~4-5us, dead rounds ~2us.
// Key = (15-rd)<<60 | d2bits<<20 | min<<10 | max: decreasing tags make stale
// parity-buffer entries lose atomicMin (winner buffers cleared once in k0;
// k0's clear->flush is same-slice-only, so syncthreads suffices).  Symmetric
// distinct keys => total edge order => hooking graph has only 2-cycles;
// dedupe by key equality; 2-cycle break inline in the chase (next==prev ->
// root=min).  Compute bodies verbatim from r5/r11 (absmax 0 in r2-r11).

#define NSAMP   32
#define NPTS    1024
#define TPB     1024
#define NROUNDS 10          // Boruvka on 1024 nodes needs <=10 rounds
#define EMPTY64 0xFFFFFFFFFFFFFFFFull

typedef unsigned long long u64;
typedef unsigned short u16;

__device__ __forceinline__ void block_sum2(float& a, float& b, float* red) {
#pragma unroll
  for (int off = 32; off > 0; off >>= 1) {
    a += __shfl_xor(a, off, 64);
    b += __shfl_xor(b, off, 64);
  }
  __syncthreads();
  const int wid = threadIdx.x >> 6;
  if ((threadIdx.x & 63) == 0) { red[wid * 2] = a; red[wid * 2 + 1] = b; }
  __syncthreads();
  float ra = 0.f, rb = 0.f;
#pragma unroll
  for (int k = 0; k < 16; ++k) { ra += red[k * 2]; rb += red[k * 2 + 1]; }
  a = ra; b = rb;
}

// r5-verbatim scan, templated on NG = nodes per (32-lane) group.
// Block covers nodes [part*NG*32, (part+1)*NG*32); 32 candidate sub-lanes.
template <int NG>
__device__ __forceinline__ void boruvka_scan(const float4* P, u64* Wl,
                                             int part, int tid, u64 tag) {
  const int g = tid >> 5, sl = tid & 31;
  const int n0 = part * (NG * 32) + g * NG;
  float mex[NG], mey[NG], mez[NG]; unsigned mc[NG];
#pragma unroll
  for (int n = 0; n < NG; ++n) {
    const float4 p = P[n0 + n];
    mex[n] = p.x; mey[n] = p.y; mez[n] = p.z; mc[n] = __float_as_uint(p.w);
  }
  float bd[NG]; int bj[NG];
#pragma unroll
  for (int n = 0; n < NG; ++n) { bd[n] = INFINITY; bj[n] = n0 + n; }
#pragma unroll 8
  for (int jj = 0; jj < 32; ++jj) {
    const int j = sl + (jj << 5);
    const float4 q = P[j];            // lanes l, l+32 share addr: broadcast
    const unsigned qc = __float_as_uint(q.w);
#pragma unroll
    for (int n = 0; n < NG; ++n) {
      const float dx = mex[n] - q.x, dy = mey[n] - q.y, dz = mez[n] - q.z;
      float d2 = dx * dx + dy * dy + dz * dz;
      d2 = (qc == mc[n]) ? INFINITY : d2;
      if (d2 < bd[n]) { bd[n] = d2; bj[n] = j; }
    }
  }
#pragma unroll
  for (int off = 16; off > 0; off >>= 1) {      // reduce 32 sub-lanes
#pragma unroll
    for (int n = 0; n < NG; ++n) {
      const float od = __shfl_xor(bd[n], off, 64);
      const int   oj = __shfl_xor(bj[n], off, 64);
      if (od < bd[n] || (od == bd[n] && oj < bj[n])) { bd[n] = od; bj[n] = oj; }
    }
  }
  if (sl == 0) {
#pragma unroll
    for (int n = 0; n < NG; ++n) {
      if (bd[n] < INFINITY) {
        const int node = n0 + n, j = bj[n];
        const unsigned a = (unsigned)(node < j ? node : j);
        const unsigned b = (unsigned)(node < j ? j : node);
        const u64 key = tag | ((u64)__float_as_uint(bd[n]) << 20)
                      | (a << 10) | b;
        atomicMin(&Wl[mc[n]], key);
      }
    }
  }
}

// ---- k0: norm + publish pts/labels + clear winners + scan round 0 ---------
__global__ __launch_bounds__(TPB) void topo_k0(
    const float* __restrict__ r, float4* __restrict__ pts4,
    u64* __restrict__ gw, u16* __restrict__ glab0,
    int* __restrict__ live_cnt, int* __restrict__ live_list0) {
  const int s = blockIdx.x & 31, part = blockIdx.x >> 5, tid = threadIdx.x;
  __shared__ float4 P[NPTS];
  __shared__ u64 Wl[NPTS];
  __shared__ float red[32];

  const float* __restrict__ base = r + (size_t)s * (NPTS * 3);
  const float px = base[tid * 3 + 0];
  const float py = base[tid * 3 + 1];
  const float pz = base[tid * 3 + 2];
  float sx = px, sy = py, sz = pz, dm = 0.f;
  block_sum2(sx, sy, red); block_sum2(sz, dm, red);
  const float mx = sx * (1.f / NPTS), my = sy * (1.f / NPTS), mz = sz * (1.f / NPTS);
  const float ex = px - mx, ey = py - my, ez = pz - mz;
  float vx = ex * ex, vy = ey * ey, vz = ez * ez;
  dm = 0.f;
  block_sum2(vx, vy, red); block_sum2(vz, dm, red);
  const float ix = 1.f / (sqrtf(vx * (1.f / NPTS)) + 1e-8f);
  const float iy = 1.f / (sqrtf(vy * (1.f / NPTS)) + 1e-8f);
  const float iz = 1.f / (sqrtf(vz * (1.f / NPTS)) + 1e-8f);
  const float4 pv =
      make_float4(ex * ix, ey * iy, ez * iz, __uint_as_float((unsigned)tid));
  P[tid] = pv;
  if (part == 0) {
    pts4[(size_t)s * NPTS + tid] = pv;
    glab0[s * NPTS + tid] = (u16)tid;               // identity labels, parity 0
    if (tid == 0) live_list0[s] = s;
  }
  if (blockIdx.x == 0 && tid <= NROUNDS)
    live_cnt[tid] = (tid == 0) ? NSAMP : 0;
  if (tid < 128) {                      // clear own slice, BOTH parities
    gw[(size_t)s * NPTS + part * 128 + tid] = EMPTY64;
    gw[(size_t)(NSAMP + s) * NPTS + part * 128 + tid] = EMPTY64;
  }
  Wl[tid] = EMPTY64;
  __syncthreads();                      // clears visible block-locally

  boruvka_scan<4>(P, Wl, part, tid, (u64)15 << 60);  // labels = identity
  __syncthreads();
  const u64 w = Wl[tid];                // non-EMPTY only within own slice
  if (w != EMPTY64) atomicMin(&gw[(size_t)s * NPTS + tid], w);
}

// ---- fused: combine(rd-1) + scan(rd), dynamic block assignment ------------
__global__ __launch_bounds__(TPB) void topo_fused(
    const float4* __restrict__ pts4, u64* __restrict__ gw,
    const u16* __restrict__ glab_r, u16* __restrict__ glab_w,
    const int* __restrict__ live_cnt_prev, int* __restrict__ live_cnt_cur,
    const int* __restrict__ live_list_prev, int* __restrict__ live_list_cur,
    float* __restrict__ totals, int rd) {
  const int n_live = live_cnt_prev[0];
  if (n_live == 0) return;
  const int bsh = (n_live <= 8) ? 5 : (n_live <= 16 ? 4 : 3);  // log2(B)
  const int idx = blockIdx.x >> bsh;
  const int part = blockIdx.x & ((1 << bsh) - 1);
  if (idx >= n_live) return;
  const int s = live_list_prev[idx];
  const int tid = threadIdx.x;

  __shared__ float4 P[NPTS];            // 16 KiB: xyz + OLD label bits in .w
  __shared__ u64 Wl[NPTS];              // 8 KiB
  __shared__ short parentL[NPTS];       // 2 KiB
  __shared__ float red[32];

  const u64* __restrict__ gwp =
      gw + (size_t)(((rd - 1) & 1) ? (NSAMP + s) : s) * NPTS;
  u64* __restrict__ gwc = gw + (size_t)((rd & 1) ? (NSAMP + s) : s) * NPTS;

  const float4 pc = pts4[(size_t)s * NPTS + tid];
  const u64 w = gwp[tid];               // boundary-coherent plain load
  const u16 ol = glab_r[s * NPTS + tid];
  Wl[tid] = w;
  P[tid] = make_float4(pc.x, pc.y, pc.z, __uint_as_float((unsigned)ol));
  __syncthreads();

  // combine slot tid (comp id), redundant per block, deterministic
  const unsigned curtag = (unsigned)(16 - rd);      // 15 - (rd-1)
  float wadd = 0.f;
  short par = (short)tid;
  if ((unsigned)(w >> 60) == curtag) {
    const int pmin = (int)((w >> 10) & 1023u);
    const int pmax = (int)(w & 1023u);
    const int cmin = (int)__float_as_uint(P[pmin].w);
    const int cmax = (int)__float_as_uint(P[pmax].w);
    const int c2 = (cmin == tid) ? cmax : cmin;
    par = (short)c2;
    const bool dup = (Wl[c2] == w);     // same undirected edge <=> same key
    if (!dup || tid < c2)
      wadd = __uint_as_float((unsigned)((w >> 20) & 0xFFFFFFFFull));
  }
  parentL[tid] = par;
  __syncthreads();
  // chase to root, inline 2-cycle break (next==prev -> root = min)
  int c = (int)__float_as_uint(P[tid].w);
  {
    int prev = -1, p = c;
    for (int it = 0; it < 1024; ++it) {
      const int nx = parentL[p];
      if (nx == p) break;
      if (nx == prev) { p = p < prev ? p : prev; break; }
      prev = p; p = nx;
    }
    c = p;
  }
  float fc = (c == tid) ? 1.f : 0.f;    // one root-node per component
  block_sum2(wadd, fc, red);
  __syncthreads();                      // all P[].w combine-reads done
  P[tid].w = __uint_as_float((unsigned)c);
  if (part == 0) {
    glab_w[s * NPTS + tid] = (u16)c;    // parity write: no reader this kernel
    if (tid == 0) {
      totals[s] = (rd == 1 ? 0.f : totals[s]) + wadd;
      if (fc > 1.5f) {
        const int pos = atomicAdd(live_cnt_cur, 1);
        live_list_cur[pos] = s;
      }
    }
  }
  if (fc == 1.f) return;                // done: skip scan (uniform per block)

  Wl[tid] = EMPTY64;
  __syncthreads();
  const u64 tag = (u64)(15 - rd) << 60;
  if (bsh == 3)      boruvka_scan<4>(P, Wl, part, tid, tag);
  else if (bsh == 4) boruvka_scan<2>(P, Wl, part, tid, tag);
  else               boruvka_scan<1>(P, Wl, part, tid, tag);
  __syncthreads();
  const u64 wn = Wl[tid];
  if (wn != EMPTY64) atomicMin(&gwc[tid], wn);
}

// ---- finish ----------------------------------------------------------------
__global__ __launch_bounds__(64) void topo_finish(
    const float* __restrict__ totals, float* __restrict__ out) {
  float v = (threadIdx.x < NSAMP) ? totals[threadIdx.x] : 0.f;
#pragma unroll
  for (int off = 32; off > 0; off >>= 1) v += __shfl_xor(v, off, 64);
  if (threadIdx.x == 0) out[0] = v * (1.f / NSAMP);
}

extern "C" void kernel_launch(void* const* d_in, const int* in_sizes, int n_in,
                              void* d_out, int out_size, void* d_ws, size_t ws_size,
                              hipStream_t stream) {
  const float* r = (const float*)d_in[0];
  float* out = (float*)d_out;
  (void)in_sizes; (void)n_in; (void)out_size; (void)ws_size;

  char* ws = (char*)d_ws;               // ~1.2 MB used (ws is ~256 MB)
  float4* pts4   = (float4*)ws;                         // 512 KiB
  u64*    gw     = (u64*)(ws + 524288);                 // 512 KiB (2 parities)
  u16*    glabA  = (u16*)(ws + 1048576);                //  64 KiB (parity 0)
  u16*    glabB  = (u16*)(ws + 1114112);                //  64 KiB (parity 1)
  float*  totals = (float*)(ws + 1179648);              // 128 B
  int*    live_cnt  = (int*)(ws + 1180160);             // (NROUNDS+1) ints
  int*    live_list = (int*)(ws + 1180224);             // (NROUNDS+1) x 32

  topo_k0<<<dim3(NSAMP * 8), dim3(TPB), 0, stream>>>(
      r, pts4, gw, glabA, live_cnt, live_list);
  for (int rd = 1; rd <= NROUNDS; ++rd) {
    u16* gr = ((rd - 1) & 1) ? glabB : glabA;
    u16* gwr = (rd & 1) ? glabB : glabA;
    topo_fused<<<dim3(256), dim3(TPB), 0, stream>>>(
        pts4, gw, gr, gwr,
        live_cnt + (rd - 1), live_cnt + rd,
        live_list + (rd - 1) * NSAMP, live_list + rd * NSAMP,
        totals, rd);
  }
  topo_finish<<<dim3(1), dim3(64), 0, stream>>>(totals, out);
}